// Round 7
// baseline (204.406 us; speedup 1.0000x reference)
//
#include <hip/hip_runtime.h>

#define IMG   256
#define SROWS 16    // output rows per block (strip)
#define KS    29
#define PAD   14
#define LDSS  292   // LDS row stride in floats; row = [0..1 unused][halo 2..15][main 16..271][halo 272..285][pad]
#define MOFF  16    // main-data float offset (layout offset = padded position + 2)

// exp(-d^2/(2*49)) for d=0..14; normalization folds at compile time.
static constexpr float GK[15] = {
    1.0f,        0.98984780f, 0.96000544f, 0.91225408f, 0.84936581f,
    0.77483743f, 0.69256933f, 0.60653066f, 0.52045012f, 0.43756474f,
    0.36044779f, 0.29092381f, 0.23006630f, 0.17826398f, 0.13533528f
};
static constexpr float GSUM =
    GK[0] + 2.0f * (GK[1] + GK[2] + GK[3] + GK[4] + GK[5] + GK[6] + GK[7] +
                    GK[8] + GK[9] + GK[10] + GK[11] + GK[12] + GK[13] + GK[14]);
static constexpr float WT[29] = {
    GK[14]/GSUM, GK[13]/GSUM, GK[12]/GSUM, GK[11]/GSUM, GK[10]/GSUM, GK[9]/GSUM, GK[8]/GSUM,
    GK[7]/GSUM,  GK[6]/GSUM,  GK[5]/GSUM,  GK[4]/GSUM,  GK[3]/GSUM,  GK[2]/GSUM, GK[1]/GSUM,
    GK[0]/GSUM,
    GK[1]/GSUM,  GK[2]/GSUM,  GK[3]/GSUM,  GK[4]/GSUM,  GK[5]/GSUM,  GK[6]/GSUM, GK[7]/GSUM,
    GK[8]/GSUM,  GK[9]/GSUM,  GK[10]/GSUM, GK[11]/GSUM, GK[12]/GSUM, GK[13]/GSUM, GK[14]/GSUM
};

__device__ __forceinline__ int refl(int p) {
    int a = p < 0 ? -p : p;        // reflect at 0
    int b = 2 * (IMG - 1) - a;     // reflect at 255
    return a < b ? a : b;
}

__global__ __launch_bounds__(256, 8)   // 64-VGPR budget, 8 blocks/CU -> 32 waves/CU
void gauss_v7(const float* __restrict__ x, float* __restrict__ out) {
    __shared__ float s[SROWS * LDSS];  // 18,688 B -> 8 blocks/CU by LDS

    const int t   = threadIdx.x;
    const int img = blockIdx.y;
    const int y0  = blockIdx.x * SROWS;

    const float* __restrict__ src = x   + (size_t)img * (IMG * IMG);
    float*       __restrict__ dst = out + (size_t)img * (IMG * IMG);

    // ---- Phase A: vertical conv. thread = (colquad cq 0..63, rowgroup rg 0..3).
    //      Each thread: 4 output rows x 4 cols; 32-row window as 4 chunks of 8
    //      independent coalesced float4 loads.
    {
        const int cq   = t & 63;
        const int rg   = t >> 6;              // wave-uniform
        const int c0   = cq * 4;
        const int brow = y0 + rg * 4 - PAD;   // first of 32 window rows

        float4 acc[4];
        #pragma unroll
        for (int j = 0; j < 4; ++j) acc[j] = make_float4(0.f, 0.f, 0.f, 0.f);

        const bool interior = (brow >= 0) && (brow + 31 < IMG);
        if (interior) {
            const float* p = src + (size_t)brow * IMG + c0;
            #pragma unroll
            for (int ch = 0; ch < 4; ++ch) {
                float4 v[8];
                #pragma unroll
                for (int i = 0; i < 8; ++i)
                    v[i] = *(const float4*)(p + (ch * 8 + i) * IMG);
                #pragma unroll
                for (int i = 0; i < 8; ++i) {
                    const int sdx = ch * 8 + i;
                    #pragma unroll
                    for (int j = 0; j < 4; ++j) {
                        const int k = sdx - j;
                        if (k >= 0 && k < KS) {
                            acc[j].x += WT[k] * v[i].x;
                            acc[j].y += WT[k] * v[i].y;
                            acc[j].z += WT[k] * v[i].z;
                            acc[j].w += WT[k] * v[i].w;
                        }
                    }
                }
            }
        } else {
            #pragma unroll
            for (int ch = 0; ch < 4; ++ch) {
                float4 v[8];
                #pragma unroll
                for (int i = 0; i < 8; ++i)
                    v[i] = *(const float4*)(src + (size_t)refl(brow + ch * 8 + i) * IMG + c0);
                #pragma unroll
                for (int i = 0; i < 8; ++i) {
                    const int sdx = ch * 8 + i;
                    #pragma unroll
                    for (int j = 0; j < 4; ++j) {
                        const int k = sdx - j;
                        if (k >= 0 && k < KS) {
                            acc[j].x += WT[k] * v[i].x;
                            acc[j].y += WT[k] * v[i].y;
                            acc[j].z += WT[k] * v[i].z;
                            acc[j].w += WT[k] * v[i].w;
                        }
                    }
                }
            }
        }

        // aligned b128 stores, lane-consecutive -> optimal
        #pragma unroll
        for (int j = 0; j < 4; ++j)
            *(float4*)&s[(rg * 4 + j) * LDSS + MOFF + c0] = acc[j];

        // mirrored horizontal halo (reflect-101):
        //   left : col c (1..14)    -> offset MOFF - c                (2..15)
        //   right: col c (241..254) -> offset MOFF + 2*(IMG-1) - c    (272..285)
        if (c0 <= PAD || c0 + 3 >= IMG - 1 - PAD) {
            #pragma unroll
            for (int q = 0; q < 4; ++q) {
                const int c = c0 + q;
                if (c >= 1 && c <= PAD) {
                    #pragma unroll
                    for (int j = 0; j < 4; ++j) {
                        const float v = q == 0 ? acc[j].x : q == 1 ? acc[j].y : q == 2 ? acc[j].z : acc[j].w;
                        s[(rg * 4 + j) * LDSS + (MOFF - c)] = v;
                    }
                } else if (c >= IMG - 1 - PAD && c <= IMG - 2) {
                    #pragma unroll
                    for (int j = 0; j < 4; ++j) {
                        const float v = q == 0 ? acc[j].x : q == 1 ? acc[j].y : q == 2 ? acc[j].z : acc[j].w;
                        s[(rg * 4 + j) * LDSS + (MOFF + 2 * (IMG - 1) - c)] = v;
                    }
                }
            }
        }
    }
    __syncthreads();

    // ---- Phase B: horizontal conv. thread = (row 0..15, colgroup 0..15).
    //      16 output cols per thread from 12 aligned b128 reads (48 floats),
    //      element-wise accumulation: element e (layout off c0+e) is padded
    //      pos c0+e-2; tap for output col c0+c is k = e-2-c.
    {
        const int row = t >> 4;
        const int cg  = t & 15;
        const int c0b = cg * 16;

        float acc[16];
        #pragma unroll
        for (int c = 0; c < 16; ++c) acc[c] = 0.f;

        const float4* w = (const float4*)&s[row * LDSS + c0b];
        #pragma unroll
        for (int ch = 0; ch < 3; ++ch) {
            float4 v[4];
            #pragma unroll
            for (int m = 0; m < 4; ++m) v[m] = w[ch * 4 + m];
            #pragma unroll
            for (int m = 0; m < 4; ++m) {
                #pragma unroll
                for (int q = 0; q < 4; ++q) {
                    const int e = (ch * 4 + m) * 4 + q;
                    const float val = q == 0 ? v[m].x : q == 1 ? v[m].y : q == 2 ? v[m].z : v[m].w;
                    #pragma unroll
                    for (int c = 0; c < 16; ++c) {
                        const int k = e - 2 - c;
                        if (k >= 0 && k < KS) acc[c] += WT[k] * val;
                    }
                }
            }
        }

        float4* orow = (float4*)&dst[(size_t)(y0 + row) * IMG + c0b];
        #pragma unroll
        for (int m = 0; m < 4; ++m)
            orow[m] = make_float4(acc[4*m+0], acc[4*m+1], acc[4*m+2], acc[4*m+3]);
    }
}

extern "C" void kernel_launch(void* const* d_in, const int* in_sizes, int n_in,
                              void* d_out, int out_size, void* d_ws, size_t ws_size,
                              hipStream_t stream) {
    const float* x = (const float*)d_in[0];
    float* out = (float*)d_out;
    const int images = in_sizes[0] / (IMG * IMG);   // 8*64 = 512
    dim3 grid(IMG / SROWS, images);                 // (16, 512)
    gauss_v7<<<grid, dim3(256), 0, stream>>>(x, out);
}

// Round 8
// 100.292 us; speedup vs baseline: 2.0381x; 2.0381x over previous
//
#include <hip/hip_runtime.h>

#define IMG   256
#define SROWS 64    // output rows per block (full-width strip)
#define KS    29
#define PAD   14
#define LDSS  292   // floats/row = 73 float4; 73 odd -> lane=row b128 reads conflict-free
#define MOFF  16    // main-data float offset (layout offset = padded position + 2)

// exp(-d^2/(2*49)) for d=0..14; normalization folds at compile time.
static constexpr float GK[15] = {
    1.0f,        0.98984780f, 0.96000544f, 0.91225408f, 0.84936581f,
    0.77483743f, 0.69256933f, 0.60653066f, 0.52045012f, 0.43756474f,
    0.36044779f, 0.29092381f, 0.23006630f, 0.17826398f, 0.13533528f
};
static constexpr float GSUM =
    GK[0] + 2.0f * (GK[1] + GK[2] + GK[3] + GK[4] + GK[5] + GK[6] + GK[7] +
                    GK[8] + GK[9] + GK[10] + GK[11] + GK[12] + GK[13] + GK[14]);
static constexpr float WT[29] = {
    GK[14]/GSUM, GK[13]/GSUM, GK[12]/GSUM, GK[11]/GSUM, GK[10]/GSUM, GK[9]/GSUM, GK[8]/GSUM,
    GK[7]/GSUM,  GK[6]/GSUM,  GK[5]/GSUM,  GK[4]/GSUM,  GK[3]/GSUM,  GK[2]/GSUM, GK[1]/GSUM,
    GK[0]/GSUM,
    GK[1]/GSUM,  GK[2]/GSUM,  GK[3]/GSUM,  GK[4]/GSUM,  GK[5]/GSUM,  GK[6]/GSUM, GK[7]/GSUM,
    GK[8]/GSUM,  GK[9]/GSUM,  GK[10]/GSUM, GK[11]/GSUM, GK[12]/GSUM, GK[13]/GSUM, GK[14]/GSUM
};

__device__ __forceinline__ int refl(int p) {
    int a = p < 0 ? -p : p;        // reflect at 0
    int b = 2 * (IMG - 1) - a;     // reflect at 255
    return a < b ? a : b;
}

__global__ __launch_bounds__(512, 4)   // cap 128 VGPR: keep 4-deep load batches, NO spills
void gauss_v8(const float* __restrict__ x, float* __restrict__ out) {
    __shared__ float s[SROWS * LDSS];  // 74,752 B -> 2 blocks/CU (16 waves)

    const int t   = threadIdx.x;
    const int img = blockIdx.y;
    const int y0  = blockIdx.x * SROWS;

    const float* __restrict__ src = x   + (size_t)img * (IMG * IMG);
    float*       __restrict__ dst = out + (size_t)img * (IMG * IMG);

    // ---- Phase A: vertical conv. thread = (colquad cq 0..63, rowgroup rg 0..7).
    //      8 output rows x 4 cols/thread; 36-row window = 9 chunks x 4 independent float4 loads.
    {
        const int cq   = t & 63;
        const int rg   = t >> 6;              // wave-uniform
        const int c0   = cq * 4;
        const int brow = y0 + rg * 8 - PAD;   // first of 36 window rows

        float4 acc[8];
        #pragma unroll
        for (int j = 0; j < 8; ++j) acc[j] = make_float4(0.f, 0.f, 0.f, 0.f);

        const bool interior = (brow >= 0) && (brow + 35 < IMG);
        if (interior) {
            const float* p = src + (size_t)brow * IMG + c0;
            #pragma unroll
            for (int ch = 0; ch < 9; ++ch) {
                float4 v[4];
                #pragma unroll
                for (int i = 0; i < 4; ++i)
                    v[i] = *(const float4*)(p + (ch * 4 + i) * IMG);
                #pragma unroll
                for (int i = 0; i < 4; ++i) {
                    const int sdx = ch * 4 + i;
                    #pragma unroll
                    for (int j = 0; j < 8; ++j) {
                        const int k = sdx - j;
                        if (k >= 0 && k < KS) {
                            acc[j].x += WT[k] * v[i].x;
                            acc[j].y += WT[k] * v[i].y;
                            acc[j].z += WT[k] * v[i].z;
                            acc[j].w += WT[k] * v[i].w;
                        }
                    }
                }
            }
        } else {
            #pragma unroll
            for (int ch = 0; ch < 9; ++ch) {
                float4 v[4];
                #pragma unroll
                for (int i = 0; i < 4; ++i)
                    v[i] = *(const float4*)(src + (size_t)refl(brow + ch * 4 + i) * IMG + c0);
                #pragma unroll
                for (int i = 0; i < 4; ++i) {
                    const int sdx = ch * 4 + i;
                    #pragma unroll
                    for (int j = 0; j < 8; ++j) {
                        const int k = sdx - j;
                        if (k >= 0 && k < KS) {
                            acc[j].x += WT[k] * v[i].x;
                            acc[j].y += WT[k] * v[i].y;
                            acc[j].z += WT[k] * v[i].z;
                            acc[j].w += WT[k] * v[i].w;
                        }
                    }
                }
            }
        }

        // aligned b128 stores; wave = 64 consecutive cq -> contiguous, conflict-free
        #pragma unroll
        for (int j = 0; j < 8; ++j)
            *(float4*)&s[(rg * 8 + j) * LDSS + MOFF + c0] = acc[j];

        // mirrored horizontal halo (reflect-101):
        //   left : col c (1..14)    -> offset MOFF - c                (2..15)
        //   right: col c (241..254) -> offset MOFF + 2*(IMG-1) - c    (272..285)
        if (c0 <= PAD || c0 + 3 >= IMG - 1 - PAD) {
            #pragma unroll
            for (int q = 0; q < 4; ++q) {
                const int c = c0 + q;
                if (c >= 1 && c <= PAD) {
                    #pragma unroll
                    for (int j = 0; j < 8; ++j) {
                        const float v = q == 0 ? acc[j].x : q == 1 ? acc[j].y : q == 2 ? acc[j].z : acc[j].w;
                        s[(rg * 8 + j) * LDSS + (MOFF - c)] = v;
                    }
                } else if (c >= IMG - 1 - PAD && c <= IMG - 2) {
                    #pragma unroll
                    for (int j = 0; j < 8; ++j) {
                        const float v = q == 0 ? acc[j].x : q == 1 ? acc[j].y : q == 2 ? acc[j].z : acc[j].w;
                        s[(rg * 8 + j) * LDSS + (MOFF + 2 * (IMG - 1) - c)] = v;
                    }
                }
            }
        }
    }
    __syncthreads();

    // ---- Phase B: horizontal conv. row = t & 63 (64 lanes, 64 distinct rows ->
    //      b128 reads at odd f4-stride 73: provably conflict-free). cg wave-uniform.
    //      2 sequential 16-col sub-blocks reuse acc/v registers.
    {
        const int row = t & 63;
        const int cg  = t >> 6;          // 0..7, wave-uniform
        #pragma unroll
        for (int sb = 0; sb < 2; ++sb) {
            const int c0b = cg * 32 + sb * 16;

            float acc[16];
            #pragma unroll
            for (int c = 0; c < 16; ++c) acc[c] = 0.f;

            const float4* w = (const float4*)&s[row * LDSS + c0b];   // 16B-aligned
            #pragma unroll
            for (int ch = 0; ch < 3; ++ch) {
                float4 v[4];
                #pragma unroll
                for (int m = 0; m < 4; ++m) v[m] = w[ch * 4 + m];
                #pragma unroll
                for (int m = 0; m < 4; ++m) {
                    #pragma unroll
                    for (int q = 0; q < 4; ++q) {
                        const int e = (ch * 4 + m) * 4 + q;          // element offset within window
                        const float val = q == 0 ? v[m].x : q == 1 ? v[m].y : q == 2 ? v[m].z : v[m].w;
                        #pragma unroll
                        for (int c = 0; c < 16; ++c) {
                            const int k = e - 2 - c;                 // tap for output col c0b+c
                            if (k >= 0 && k < KS) acc[c] += WT[k] * val;
                        }
                    }
                }
            }

            float4* orow = (float4*)&dst[(size_t)(y0 + row) * IMG + c0b];
            #pragma unroll
            for (int m = 0; m < 4; ++m)
                orow[m] = make_float4(acc[4*m+0], acc[4*m+1], acc[4*m+2], acc[4*m+3]);
        }
    }
}

extern "C" void kernel_launch(void* const* d_in, const int* in_sizes, int n_in,
                              void* d_out, int out_size, void* d_ws, size_t ws_size,
                              hipStream_t stream) {
    const float* x = (const float*)d_in[0];
    float* out = (float*)d_out;
    const int images = in_sizes[0] / (IMG * IMG);   // 8*64 = 512
    dim3 grid(IMG / SROWS, images);                 // (4, 512)
    gauss_v8<<<grid, dim3(512), 0, stream>>>(x, out);
}

// Round 9
// 95.936 us; speedup vs baseline: 2.1307x; 1.0454x over previous
//
#include <hip/hip_runtime.h>

#define IMG   256
#define SROWS 64    // output rows per block (full-width strip)
#define KS    29
#define PAD   14
#define LDSS  292   // floats/row = 73 float4; odd -> lane=row b128 reads conflict-free
#define MOFF  16    // main-data float offset (layout offset = padded position + 2)

// exp(-d^2/(2*49)) for d=0..14; normalization folds at compile time.
static constexpr float GK[15] = {
    1.0f,        0.98984780f, 0.96000544f, 0.91225408f, 0.84936581f,
    0.77483743f, 0.69256933f, 0.60653066f, 0.52045012f, 0.43756474f,
    0.36044779f, 0.29092381f, 0.23006630f, 0.17826398f, 0.13533528f
};
static constexpr float GSUM =
    GK[0] + 2.0f * (GK[1] + GK[2] + GK[3] + GK[4] + GK[5] + GK[6] + GK[7] +
                    GK[8] + GK[9] + GK[10] + GK[11] + GK[12] + GK[13] + GK[14]);
static constexpr float WT[29] = {
    GK[14]/GSUM, GK[13]/GSUM, GK[12]/GSUM, GK[11]/GSUM, GK[10]/GSUM, GK[9]/GSUM, GK[8]/GSUM,
    GK[7]/GSUM,  GK[6]/GSUM,  GK[5]/GSUM,  GK[4]/GSUM,  GK[3]/GSUM,  GK[2]/GSUM, GK[1]/GSUM,
    GK[0]/GSUM,
    GK[1]/GSUM,  GK[2]/GSUM,  GK[3]/GSUM,  GK[4]/GSUM,  GK[5]/GSUM,  GK[6]/GSUM, GK[7]/GSUM,
    GK[8]/GSUM,  GK[9]/GSUM,  GK[10]/GSUM, GK[11]/GSUM, GK[12]/GSUM, GK[13]/GSUM, GK[14]/GSUM
};

__device__ __forceinline__ int refl(int p) {
    int a = p < 0 ? -p : p;        // reflect at 0
    int b = 2 * (IMG - 1) - a;     // reflect at 255
    return a < b ? a : b;
}

// ---- Phase A helper: vertical conv with double-buffered (1-ahead) load pipeline.
template<bool INTERIOR>
__device__ __forceinline__ void phaseA(const float* __restrict__ src, float* __restrict__ s,
                                       int y0, int rg, int c0) {
    const int brow = y0 + rg * 8 - PAD;   // first of 36 window rows

    float4 acc[8];
    #pragma unroll
    for (int j = 0; j < 8; ++j) acc[j] = make_float4(0.f, 0.f, 0.f, 0.f);

    float4 vA[4], vB[4];

    // address of window row sdx (compile-time sdx under full unroll)
    #define AADDR(sdx) ((const float4*)(src + (size_t)(INTERIOR ? (brow + (sdx)) \
                                        : refl(brow + (sdx))) * IMG + c0))
    #define AFMA(buf, ch)                                                      \
        {   _Pragma("unroll")                                                  \
            for (int i = 0; i < 4; ++i) {                                      \
                const int sdx = (ch) * 4 + i;                                  \
                _Pragma("unroll")                                              \
                for (int j = 0; j < 8; ++j) {                                  \
                    const int k = sdx - j;                                     \
                    if (k >= 0 && k < KS) {                                    \
                        acc[j].x += WT[k] * buf[i].x;                          \
                        acc[j].y += WT[k] * buf[i].y;                          \
                        acc[j].z += WT[k] * buf[i].z;                          \
                        acc[j].w += WT[k] * buf[i].w;                          \
                    }                                                          \
                }                                                              \
            }                                                                  \
        }

    // prologue: batch 0 -> vA
    #pragma unroll
    for (int i = 0; i < 4; ++i) vA[i] = *AADDR(i);

    // steady state: issue batch ch+1 into the idle buffer BEFORE consuming batch ch
    #pragma unroll
    for (int ch = 0; ch < 9; ++ch) {
        if ((ch & 1) == 0) {
            if (ch < 8) {
                #pragma unroll
                for (int i = 0; i < 4; ++i) vB[i] = *AADDR((ch + 1) * 4 + i);
            }
            AFMA(vA, ch);
        } else {
            if (ch < 8) {
                #pragma unroll
                for (int i = 0; i < 4; ++i) vA[i] = *AADDR((ch + 1) * 4 + i);
            }
            AFMA(vB, ch);
        }
    }
    #undef AADDR
    #undef AFMA

    // aligned b128 stores; wave = 64 consecutive col-quads -> contiguous, conflict-free
    #pragma unroll
    for (int j = 0; j < 8; ++j)
        *(float4*)&s[(rg * 8 + j) * LDSS + MOFF + c0] = acc[j];

    // mirrored horizontal halo (reflect-101):
    //   left : col c (1..14)    -> offset MOFF - c                (2..15)
    //   right: col c (241..254) -> offset MOFF + 2*(IMG-1) - c    (272..285)
    if (c0 <= PAD || c0 + 3 >= IMG - 1 - PAD) {
        #pragma unroll
        for (int q = 0; q < 4; ++q) {
            const int c = c0 + q;
            if (c >= 1 && c <= PAD) {
                #pragma unroll
                for (int j = 0; j < 8; ++j) {
                    const float v = q == 0 ? acc[j].x : q == 1 ? acc[j].y : q == 2 ? acc[j].z : acc[j].w;
                    s[(rg * 8 + j) * LDSS + (MOFF - c)] = v;
                }
            } else if (c >= IMG - 1 - PAD && c <= IMG - 2) {
                #pragma unroll
                for (int j = 0; j < 8; ++j) {
                    const float v = q == 0 ? acc[j].x : q == 1 ? acc[j].y : q == 2 ? acc[j].z : acc[j].w;
                    s[(rg * 8 + j) * LDSS + (MOFF + 2 * (IMG - 1) - c)] = v;
                }
            }
        }
    }
}

__global__ __launch_bounds__(512, 4)   // cap 128 VGPR: room for dbuf pipeline, no spills
void gauss_v9(const float* __restrict__ x, float* __restrict__ out) {
    __shared__ float s[SROWS * LDSS];  // 74,752 B -> 2 blocks/CU

    const int t   = threadIdx.x;
    const int img = blockIdx.y;
    const int y0  = blockIdx.x * SROWS;

    const float* __restrict__ src = x   + (size_t)img * (IMG * IMG);
    float*       __restrict__ dst = out + (size_t)img * (IMG * IMG);

    // ---- Phase A: thread = (colquad cq 0..63, rowgroup rg 0..7 wave-uniform).
    {
        const int cq = t & 63;
        const int rg = t >> 6;
        const int c0 = cq * 4;
        const int brow = y0 + rg * 8 - PAD;
        if (brow >= 0 && brow + 35 < IMG) phaseA<true >(src, s, y0, rg, c0);
        else                              phaseA<false>(src, s, y0, rg, c0);
    }
    __syncthreads();

    // ---- Phase B: horizontal conv. row = t & 63 (conflict-free b128 at odd f4-stride 73),
    //      cg wave-uniform; 2 sequential 16-col sub-blocks; LDS reads double-buffered.
    {
        const int row = t & 63;
        const int cg  = t >> 6;          // 0..7, wave-uniform
        #pragma unroll
        for (int sb = 0; sb < 2; ++sb) {
            const int c0b = cg * 32 + sb * 16;

            float acc[16];
            #pragma unroll
            for (int c = 0; c < 16; ++c) acc[c] = 0.f;

            const float4* w = (const float4*)&s[row * LDSS + c0b];   // 16B-aligned
            float4 uA[4], uB[4];

            #define BFMA(buf, ch)                                                  \
                {   _Pragma("unroll")                                              \
                    for (int m = 0; m < 4; ++m) {                                  \
                        _Pragma("unroll")                                          \
                        for (int q = 0; q < 4; ++q) {                              \
                            const int e = ((ch) * 4 + m) * 4 + q;                  \
                            const float val = q == 0 ? buf[m].x : q == 1 ? buf[m].y\
                                            : q == 2 ? buf[m].z : buf[m].w;        \
                            _Pragma("unroll")                                      \
                            for (int c = 0; c < 16; ++c) {                         \
                                const int k = e - 2 - c;                           \
                                if (k >= 0 && k < KS) acc[c] += WT[k] * val;       \
                            }                                                      \
                        }                                                          \
                    }                                                              \
                }

            #pragma unroll
            for (int m = 0; m < 4; ++m) uA[m] = w[m];
            #pragma unroll
            for (int ch = 0; ch < 3; ++ch) {
                if ((ch & 1) == 0) {
                    if (ch < 2) {
                        #pragma unroll
                        for (int m = 0; m < 4; ++m) uB[m] = w[(ch + 1) * 4 + m];
                    }
                    BFMA(uA, ch);
                } else {
                    if (ch < 2) {
                        #pragma unroll
                        for (int m = 0; m < 4; ++m) uA[m] = w[(ch + 1) * 4 + m];
                    }
                    BFMA(uB, ch);
                }
            }
            #undef BFMA

            float4* orow = (float4*)&dst[(size_t)(y0 + row) * IMG + c0b];
            #pragma unroll
            for (int m = 0; m < 4; ++m)
                orow[m] = make_float4(acc[4*m+0], acc[4*m+1], acc[4*m+2], acc[4*m+3]);
        }
    }
}

extern "C" void kernel_launch(void* const* d_in, const int* in_sizes, int n_in,
                              void* d_out, int out_size, void* d_ws, size_t ws_size,
                              hipStream_t stream) {
    const float* x = (const float*)d_in[0];
    float* out = (float*)d_out;
    const int images = in_sizes[0] / (IMG * IMG);   // 8*64 = 512
    dim3 grid(IMG / SROWS, images);                 // (4, 512)
    gauss_v9<<<grid, dim3(512), 0, stream>>>(x, out);
}

// Round 10
// 91.268 us; speedup vs baseline: 2.2396x; 1.0511x over previous
//
#include <hip/hip_runtime.h>

#define IMG   256
#define SROWS 64    // output rows per block (full-width strip)
#define KS    29
#define PAD   14
#define LDSS  292   // floats/row; row = [0..1 pad][halo 2..15][main 16..271][halo 272..285][pad]
#define MOFF  16    // main-data float offset (layout offset = padded position + 2)

// exp(-d^2/(2*49)) for d=0..14; normalization folds at compile time.
static constexpr float GK[15] = {
    1.0f,        0.98984780f, 0.96000544f, 0.91225408f, 0.84936581f,
    0.77483743f, 0.69256933f, 0.60653066f, 0.52045012f, 0.43756474f,
    0.36044779f, 0.29092381f, 0.23006630f, 0.17826398f, 0.13533528f
};
static constexpr float GSUM =
    GK[0] + 2.0f * (GK[1] + GK[2] + GK[3] + GK[4] + GK[5] + GK[6] + GK[7] +
                    GK[8] + GK[9] + GK[10] + GK[11] + GK[12] + GK[13] + GK[14]);
static constexpr float WT[29] = {
    GK[14]/GSUM, GK[13]/GSUM, GK[12]/GSUM, GK[11]/GSUM, GK[10]/GSUM, GK[9]/GSUM, GK[8]/GSUM,
    GK[7]/GSUM,  GK[6]/GSUM,  GK[5]/GSUM,  GK[4]/GSUM,  GK[3]/GSUM,  GK[2]/GSUM, GK[1]/GSUM,
    GK[0]/GSUM,
    GK[1]/GSUM,  GK[2]/GSUM,  GK[3]/GSUM,  GK[4]/GSUM,  GK[5]/GSUM,  GK[6]/GSUM, GK[7]/GSUM,
    GK[8]/GSUM,  GK[9]/GSUM,  GK[10]/GSUM, GK[11]/GSUM, GK[12]/GSUM, GK[13]/GSUM, GK[14]/GSUM
};

__device__ __forceinline__ int refl(int p) {
    int a = p < 0 ? -p : p;        // reflect at 0
    int b = 2 * (IMG - 1) - a;     // reflect at 255
    return a < b ? a : b;
}

// ---- Phase A: vertical conv, 4 output rows x 4 cols per thread.
//      32-row window = 8 chunks x 4 independent float4 loads, 1-ahead prefetch.
template<bool INTERIOR>
__device__ __forceinline__ void phaseA(const float* __restrict__ src, float* __restrict__ s,
                                       int brow, int rg, int c0) {
    float4 acc[4];
    #pragma unroll
    for (int j = 0; j < 4; ++j) acc[j] = make_float4(0.f, 0.f, 0.f, 0.f);

    float4 vA[4], vB[4];

    #define AADDR(sdx) ((const float4*)(src + (size_t)(INTERIOR ? (brow + (sdx)) \
                                        : refl(brow + (sdx))) * IMG + c0))
    #define AFMA(buf, ch)                                                      \
        {   _Pragma("unroll")                                                  \
            for (int i = 0; i < 4; ++i) {                                      \
                const int sdx = (ch) * 4 + i;                                  \
                _Pragma("unroll")                                              \
                for (int j = 0; j < 4; ++j) {                                  \
                    const int k = sdx - j;                                     \
                    if (k >= 0 && k < KS) {                                    \
                        acc[j].x += WT[k] * buf[i].x;                          \
                        acc[j].y += WT[k] * buf[i].y;                          \
                        acc[j].z += WT[k] * buf[i].z;                          \
                        acc[j].w += WT[k] * buf[i].w;                          \
                    }                                                          \
                }                                                              \
            }                                                                  \
        }

    #pragma unroll
    for (int i = 0; i < 4; ++i) vA[i] = *AADDR(i);

    #pragma unroll
    for (int ch = 0; ch < 8; ++ch) {
        if ((ch & 1) == 0) {
            if (ch < 7) {
                #pragma unroll
                for (int i = 0; i < 4; ++i) vB[i] = *AADDR((ch + 1) * 4 + i);
            }
            AFMA(vA, ch);
        } else {
            if (ch < 7) {
                #pragma unroll
                for (int i = 0; i < 4; ++i) vA[i] = *AADDR((ch + 1) * 4 + i);
            }
            AFMA(vB, ch);
        }
    }
    #undef AADDR
    #undef AFMA

    // aligned b128 stores; 64 consecutive col-quads per wave -> contiguous, conflict-free
    #pragma unroll
    for (int j = 0; j < 4; ++j)
        *(float4*)&s[(rg * 4 + j) * LDSS + MOFF + c0] = acc[j];

    // mirrored horizontal halo (reflect-101):
    //   left : col c (1..14)    -> offset MOFF - c                (2..15)
    //   right: col c (241..254) -> offset MOFF + 2*(IMG-1) - c    (272..285)
    if (c0 <= PAD || c0 + 3 >= IMG - 1 - PAD) {
        #pragma unroll
        for (int q = 0; q < 4; ++q) {
            const int c = c0 + q;
            if (c >= 1 && c <= PAD) {
                #pragma unroll
                for (int j = 0; j < 4; ++j) {
                    const float v = q == 0 ? acc[j].x : q == 1 ? acc[j].y : q == 2 ? acc[j].z : acc[j].w;
                    s[(rg * 4 + j) * LDSS + (MOFF - c)] = v;
                }
            } else if (c >= IMG - 1 - PAD && c <= IMG - 2) {
                #pragma unroll
                for (int j = 0; j < 4; ++j) {
                    const float v = q == 0 ? acc[j].x : q == 1 ? acc[j].y : q == 2 ? acc[j].z : acc[j].w;
                    s[(rg * 4 + j) * LDSS + (MOFF + 2 * (IMG - 1) - c)] = v;
                }
            }
        }
    }
}

__global__ __launch_bounds__(1024, 4)   // cap 128 VGPR (no forced spill); natural alloc ~60
void gauss_v10(const float* __restrict__ x, float* __restrict__ out) {
    __shared__ float s[SROWS * LDSS];   // 74,752 B; 2 blocks x 16 waves = 32 waves/CU if VGPR<=64

    const int t   = threadIdx.x;
    const int img = blockIdx.y;
    const int y0  = blockIdx.x * SROWS;

    const float* __restrict__ src = x   + (size_t)img * (IMG * IMG);
    float*       __restrict__ dst = out + (size_t)img * (IMG * IMG);

    // ---- Phase A: thread = (colquad cq 0..63, rowgroup rg 0..15 wave-uniform).
    {
        const int cq = t & 63;
        const int rg = t >> 6;
        const int c0 = cq * 4;
        const int brow = y0 + rg * 4 - PAD;
        if (brow >= 0 && brow + 31 < IMG) phaseA<true >(src, s, brow, rg, c0);
        else                              phaseA<false>(src, s, brow, rg, c0);
    }
    __syncthreads();

    // ---- Phase B: horizontal conv. row = t & 63 (lane=row), cg = t>>6 wave-uniform.
    //      16 output cols/thread from 12 aligned b128 reads, 1-ahead staged.
    {
        const int row = t & 63;
        const int cg  = t >> 6;          // 0..15
        const int c0b = cg * 16;

        float acc[16];
        #pragma unroll
        for (int c = 0; c < 16; ++c) acc[c] = 0.f;

        const float4* w = (const float4*)&s[row * LDSS + c0b];   // 16B-aligned
        float4 uA[4], uB[4];

        #define BFMA(buf, ch)                                                  \
            {   _Pragma("unroll")                                              \
                for (int m = 0; m < 4; ++m) {                                  \
                    _Pragma("unroll")                                          \
                    for (int q = 0; q < 4; ++q) {                              \
                        const int e = ((ch) * 4 + m) * 4 + q;                  \
                        const float val = q == 0 ? buf[m].x : q == 1 ? buf[m].y\
                                        : q == 2 ? buf[m].z : buf[m].w;        \
                        _Pragma("unroll")                                      \
                        for (int c = 0; c < 16; ++c) {                         \
                            const int k = e - 2 - c;                           \
                            if (k >= 0 && k < KS) acc[c] += WT[k] * val;       \
                        }                                                      \
                    }                                                          \
                }                                                              \
            }

        #pragma unroll
        for (int m = 0; m < 4; ++m) uA[m] = w[m];
        #pragma unroll
        for (int ch = 0; ch < 3; ++ch) {
            if ((ch & 1) == 0) {
                if (ch < 2) {
                    #pragma unroll
                    for (int m = 0; m < 4; ++m) uB[m] = w[(ch + 1) * 4 + m];
                }
                BFMA(uA, ch);
            } else {
                if (ch < 2) {
                    #pragma unroll
                    for (int m = 0; m < 4; ++m) uA[m] = w[(ch + 1) * 4 + m];
                }
                BFMA(uB, ch);
            }
        }
        #undef BFMA

        float4* orow = (float4*)&dst[(size_t)(y0 + row) * IMG + c0b];
        #pragma unroll
        for (int m = 0; m < 4; ++m)
            orow[m] = make_float4(acc[4*m+0], acc[4*m+1], acc[4*m+2], acc[4*m+3]);
    }
}

extern "C" void kernel_launch(void* const* d_in, const int* in_sizes, int n_in,
                              void* d_out, int out_size, void* d_ws, size_t ws_size,
                              hipStream_t stream) {
    const float* x = (const float*)d_in[0];
    float* out = (float*)d_out;
    const int images = in_sizes[0] / (IMG * IMG);   // 8*64 = 512
    dim3 grid(IMG / SROWS, images);                 // (4, 512)
    gauss_v10<<<grid, dim3(1024), 0, stream>>>(x, out);
}